// Round 2
// baseline (243.941 us; speedup 1.0000x reference)
//
#include <hip/hip_runtime.h>
#include <stdint.h>

#define IN_F 4096
#define OUT_F 11008
#define NUM_CH 128
#define NUM_NORM 3968
#define QROWS 1984
#define BATCH 64
#define BS 40   // padded k-stride of LDS B tile, in shorts (80 B: 16B-aligned, 20-bank stride)

typedef short short8 __attribute__((ext_vector_type(8)));
typedef float float4v __attribute__((ext_vector_type(4)));
typedef int int4v __attribute__((ext_vector_type(4)));

__device__ __forceinline__ unsigned short f2bf(float f) {
    union { float f; unsigned u; } v; v.f = f;
    unsigned u = v.u;
    return (unsigned short)((u + 0x7FFFu + ((u >> 16) & 1u)) >> 16);
}

// Gather-permute x into bf16 xp[64][4096]:
//   pos j in [0,3968): x[:, normal_idx[j]]  (complement of cherries, ascending)
//   pos 3968+c       : x[:, cherry_indices[c]]
__global__ __launch_bounds__(256) void permute_x(
        const float* __restrict__ x, const int* __restrict__ cidx,
        unsigned short* __restrict__ xp) {
    int i = blockIdx.x * blockDim.x + threadIdx.x;   // input column 0..4095
    int b = blockIdx.y;                               // batch row 0..63
    int lo = 0, hi = NUM_CH;
    while (lo < hi) { int mid = (lo + hi) >> 1; if (cidx[mid] < i) lo = mid + 1; else hi = mid; }
    bool isch = (lo < NUM_CH) && (cidx[lo] == i);
    int pos = isch ? (NUM_NORM + lo) : (i - lo);
    xp[b * IN_F + pos] = f2bf(x[b * IN_F + i]);
}

// Fused dequant + bf16 MFMA GEMM: out[64][11008] = xp @ B + bias
// qweight arrives as int32 per element (harness widens integer inputs), one
// packed byte (two nibbles) per int. B[k][n]: k<3968 -> dequant int4;
// k>=3968 -> cherry_weight rows (fp32 -> bf16).
__global__ __launch_bounds__(256) void qgemm(
        const unsigned short* __restrict__ xp, const int* __restrict__ qw,
        const float* __restrict__ cw, const float* __restrict__ scales,
        const float* __restrict__ bias, float* __restrict__ out) {
    __shared__ unsigned short Bt[64][BS];   // [n][k] bf16, k contiguous for b128 frag reads

    const int n0 = blockIdx.x * 64;
    const int tid = threadIdx.x;
    const int wave = tid >> 6;
    const int lane = tid & 63;
    const int ln = lane & 15;   // fragment row/col index
    const int lq = lane >> 4;   // quad 0..3

    float4v acc[4];
    #pragma unroll
    for (int s = 0; s < 4; ++s) acc[s] = (float4v){0.f, 0.f, 0.f, 0.f};

    // staging assignment: lanes 0..15 cover 64 consecutive int32 of one row
    const int row = tid >> 4;          // packed row 0..15 within 16-row chunk
    const int col = (tid & 15) << 2;   // col offset 0..60, 4 ints per thread

    for (int k0 = 0; k0 < IN_F; k0 += 32) {
        if (k0 < NUM_NORM) {
            // quantized region: 16 packed rows x 64 cols of int32 -> 32x64 weights
            const int rbase = k0 >> 1;
            const int4v q4 = *reinterpret_cast<const int4v*>(
                qw + (size_t)(rbase + row) * OUT_F + n0 + col);
            const int g = k0 >> 7;  // 32-chunk always within one 128-group
            const float4v s4 = *reinterpret_cast<const float4v*>(
                scales + (size_t)g * OUT_F + n0 + col);
            const int kk = row * 2;
            #pragma unroll
            for (int c = 0; c < 4; ++c) {
                const int q = q4[c];
                const float sc = s4[c];
                const float w0 = (float)((q & 0xF) - 8) * sc;         // low nibble = even k
                const float w1 = (float)(((q >> 4) & 0xF) - 8) * sc;  // high nibble = odd k
                const unsigned packed = (unsigned)f2bf(w0) | ((unsigned)f2bf(w1) << 16);
                *reinterpret_cast<unsigned*>(&Bt[col + c][kk]) = packed;
            }
        } else {
            // cherry region: 32 rows x 64 cols fp32 -> bf16
            const int kk = tid >> 3;           // 0..31
            const int cc = (tid & 7) << 3;     // 0..56
            const float* p = cw + (size_t)(k0 - NUM_NORM + kk) * OUT_F + n0 + cc;
            #pragma unroll
            for (int c = 0; c < 8; ++c) Bt[cc + c][kk] = f2bf(p[c]);
        }
        __syncthreads();

        // A fragment: A[m = wave*16 + ln][k = k0 + lq*8 + j]
        const int m = (wave << 4) + ln;
        const short8 a = *reinterpret_cast<const short8*>(
            xp + (size_t)m * IN_F + k0 + (lq << 3));
        #pragma unroll
        for (int st = 0; st < 4; ++st) {
            const short8 b = *reinterpret_cast<const short8*>(&Bt[(st << 4) + ln][lq << 3]);
            acc[st] = __builtin_amdgcn_mfma_f32_16x16x32_bf16(a, b, acc[st], 0, 0, 0);
        }
        __syncthreads();
    }

    // Epilogue: D col = ln (n), row = lq*4 + r (m within wave's 16-row tile)
    #pragma unroll
    for (int st = 0; st < 4; ++st) {
        const int n = n0 + (st << 4) + ln;
        const float bv = bias[n];
        #pragma unroll
        for (int r = 0; r < 4; ++r) {
            const int mm = (wave << 4) + (lq << 2) + r;
            out[(size_t)mm * OUT_F + n] = acc[st][r] + bv;
        }
    }
}

extern "C" void kernel_launch(void* const* d_in, const int* in_sizes, int n_in,
                              void* d_out, int out_size, void* d_ws, size_t ws_size,
                              hipStream_t stream) {
    const float* x      = (const float*)d_in[0];
    const int*   qw     = (const int*)d_in[1];     // uint8 widened to int32 by harness
    const float* cw     = (const float*)d_in[2];
    const int*   cidx   = (const int*)d_in[3];
    const float* scales = (const float*)d_in[4];
    const float* bias   = (const float*)d_in[5];
    float*       out    = (float*)d_out;
    unsigned short* xp  = (unsigned short*)d_ws;   // 64*4096 bf16 = 512 KB

    dim3 pgrid(IN_F / 256, BATCH);
    permute_x<<<pgrid, 256, 0, stream>>>(x, cidx, xp);
    qgemm<<<OUT_F / 64, 256, 0, stream>>>(xp, qw, cw, scales, bias, out);
}

// Round 3
// 168.368 us; speedup vs baseline: 1.4489x; 1.4489x over previous
//
#include <hip/hip_runtime.h>
#include <stdint.h>

#define IN_F 4096
#define OUT_F 11008
#define NUM_CH 128
#define NUM_NORM 3968
#define QROWS 1984
#define BATCH 64
#define BS 40      // padded k-stride of LDS B tile, in shorts (80 B: 16B-aligned)
#define KSPLIT 8
#define KCHUNK (IN_F / KSPLIT)   // 512

typedef short short8 __attribute__((ext_vector_type(8)));
typedef float float4v __attribute__((ext_vector_type(4)));
typedef int int4v __attribute__((ext_vector_type(4)));

__device__ __forceinline__ unsigned short f2bf(float f) {
    union { float f; unsigned u; } v; v.f = f;
    unsigned u = v.u;
    return (unsigned short)((u + 0x7FFFu + ((u >> 16) & 1u)) >> 16);
}

// out[m][n] = bias[n]  (pre-init so qgemm can atomicAdd partials)
__global__ __launch_bounds__(256) void init_out(
        const float* __restrict__ bias, float* __restrict__ out) {
    const int i = blockIdx.x * 256 + threadIdx.x;        // float4 index
    const int c = i % (OUT_F / 4);
    const float4v b4 = *reinterpret_cast<const float4v*>(bias + c * 4);
    reinterpret_cast<float4v*>(out)[i] = b4;
}

// Gather-permute x into bf16 xp[64][4096]:
//   pos j in [0,3968): x[:, normal_idx[j]]  (complement of cherries, ascending)
//   pos 3968+c       : x[:, cherry_indices[c]]
__global__ __launch_bounds__(256) void permute_x(
        const float* __restrict__ x, const int* __restrict__ cidx,
        unsigned short* __restrict__ xp) {
    int i = blockIdx.x * blockDim.x + threadIdx.x;   // input column 0..4095
    int b = blockIdx.y;                               // batch row 0..63
    int lo = 0, hi = NUM_CH;
    while (lo < hi) { int mid = (lo + hi) >> 1; if (cidx[mid] < i) lo = mid + 1; else hi = mid; }
    bool isch = (lo < NUM_CH) && (cidx[lo] == i);
    int pos = isch ? (NUM_NORM + lo) : (i - lo);
    xp[b * IN_F + pos] = f2bf(x[b * IN_F + i]);
}

struct StageRegs {
    int4v q4;            // 4 packed bytes (widened to int32) of one qweight row
    float4v s4;          // matching per-group scales
    float4v c0, c1;      // cherry path: 8 fp32 weights
};

// Fused dequant + bf16 MFMA GEMM with K-split + register prefetch pipeline.
// Block (bx, ky): N-tile [bx*64, bx*64+64), K-chunk [ky*512, ky*512+512).
// Partial 64x64 tile atomically added into out (pre-initialized with bias).
__global__ __launch_bounds__(256) void qgemm(
        const unsigned short* __restrict__ xp, const int* __restrict__ qw,
        const float* __restrict__ cw, const float* __restrict__ scales,
        float* __restrict__ out) {
    __shared__ unsigned short Bt[64][BS];   // [n][k] bf16

    const int n0 = blockIdx.x * 64;
    const int kbase = blockIdx.y * KCHUNK;
    const int tid = threadIdx.x;
    const int wave = tid >> 6;
    const int lane = tid & 63;
    const int ln = lane & 15;   // fragment row/col index
    const int lq = lane >> 4;   // quad 0..3

    // staging mappings
    const int row = tid >> 4;          // packed row 0..15 within 16-row chunk
    const int col = (tid & 15) << 2;   // col offset 0..60, 4 elems per thread
    const int ckk = tid >> 3;          // cherry: k row 0..31
    const int ccc = (tid & 7) << 3;    // cherry: col offset 0..56

    float4v acc[4];
    #pragma unroll
    for (int s = 0; s < 4; ++s) acc[s] = (float4v){0.f, 0.f, 0.f, 0.f};

    const int m = (wave << 4) + ln;    // batch row for A fragment
    const unsigned short* aptr = xp + (size_t)m * IN_F + (lq << 3);

    StageRegs sr;
    // prologue: load step 0
    {
        const int k0 = kbase;
        if (k0 < NUM_NORM) {
            sr.q4 = *reinterpret_cast<const int4v*>(
                qw + (size_t)((k0 >> 1) + row) * OUT_F + n0 + col);
            sr.s4 = *reinterpret_cast<const float4v*>(
                scales + (size_t)(k0 >> 7) * OUT_F + n0 + col);
        } else {
            const float* p = cw + (size_t)(k0 - NUM_NORM + ckk) * OUT_F + n0 + ccc;
            sr.c0 = *reinterpret_cast<const float4v*>(p);
            sr.c1 = *reinterpret_cast<const float4v*>(p + 4);
        }
    }
    short8 a_next = *reinterpret_cast<const short8*>(aptr + kbase);

    for (int i = 0; i < KCHUNK / 32; ++i) {
        const int k0 = kbase + (i << 5);
        // commit staged regs -> LDS
        if (k0 < NUM_NORM) {
            const int kk = row * 2;
            #pragma unroll
            for (int c = 0; c < 4; ++c) {
                const int q = sr.q4[c];
                const float sc = sr.s4[c];
                const float w0 = (float)((q & 0xF) - 8) * sc;         // even k
                const float w1 = (float)(((q >> 4) & 0xF) - 8) * sc;  // odd k
                const unsigned packed = (unsigned)f2bf(w0) | ((unsigned)f2bf(w1) << 16);
                *reinterpret_cast<unsigned*>(&Bt[col + c][kk]) = packed;
            }
        } else {
            const float cv[8] = {sr.c0[0], sr.c0[1], sr.c0[2], sr.c0[3],
                                 sr.c1[0], sr.c1[1], sr.c1[2], sr.c1[3]};
            #pragma unroll
            for (int c = 0; c < 8; ++c) Bt[ccc + c][ckk] = f2bf(cv[c]);
        }
        __syncthreads();

        const short8 a = a_next;
        // prefetch next step's global data while MFMAs run
        if (i + 1 < KCHUNK / 32) {
            const int kn = k0 + 32;
            if (kn < NUM_NORM) {
                sr.q4 = *reinterpret_cast<const int4v*>(
                    qw + (size_t)((kn >> 1) + row) * OUT_F + n0 + col);
                sr.s4 = *reinterpret_cast<const float4v*>(
                    scales + (size_t)(kn >> 7) * OUT_F + n0 + col);
            } else {
                const float* p = cw + (size_t)(kn - NUM_NORM + ckk) * OUT_F + n0 + ccc;
                sr.c0 = *reinterpret_cast<const float4v*>(p);
                sr.c1 = *reinterpret_cast<const float4v*>(p + 4);
            }
            a_next = *reinterpret_cast<const short8*>(aptr + kn);
        }

        #pragma unroll
        for (int st = 0; st < 4; ++st) {
            const short8 b = *reinterpret_cast<const short8*>(&Bt[(st << 4) + ln][lq << 3]);
            acc[st] = __builtin_amdgcn_mfma_f32_16x16x32_bf16(a, b, acc[st], 0, 0, 0);
        }
        __syncthreads();
    }

    // Epilogue: D col = ln (n), row = lq*4 + r; atomic-accumulate partials
    #pragma unroll
    for (int st = 0; st < 4; ++st) {
        const int n = n0 + (st << 4) + ln;
        #pragma unroll
        for (int r = 0; r < 4; ++r) {
            const int mm = (wave << 4) + (lq << 2) + r;
            atomicAdd(&out[(size_t)mm * OUT_F + n], acc[st][r]);
        }
    }
}

extern "C" void kernel_launch(void* const* d_in, const int* in_sizes, int n_in,
                              void* d_out, int out_size, void* d_ws, size_t ws_size,
                              hipStream_t stream) {
    const float* x      = (const float*)d_in[0];
    const int*   qw     = (const int*)d_in[1];     // uint8 widened to int32 by harness
    const float* cw     = (const float*)d_in[2];
    const int*   cidx   = (const int*)d_in[3];
    const float* scales = (const float*)d_in[4];
    const float* bias   = (const float*)d_in[5];
    float*       out    = (float*)d_out;
    unsigned short* xp  = (unsigned short*)d_ws;   // 64*4096 bf16 = 512 KB

    init_out<<<(BATCH * OUT_F / 4) / 256, 256, 0, stream>>>(bias, out);
    dim3 pgrid(IN_F / 256, BATCH);
    permute_x<<<pgrid, 256, 0, stream>>>(x, cidx, xp);
    qgemm<<<dim3(OUT_F / 64, KSPLIT), 256, 0, stream>>>(xp, qw, cw, scales, out);
}